// Round 1
// baseline (27161.655 us; speedup 1.0000x reference)
//
#include <hip/hip_runtime.h>
#include <hip/hip_bf16.h>

#define BB 32
#define SS 64
#define TT 63
#define EMBD 512
#define ENCD 1024
#define HIDD 1024
#define VV 32000
#define INTERD 2160
#define G4 4096
#define LIND 2560
#define TV (TT*VV)            /* 2,016,000 */
#define OUT_ATT ((long)BB*TT*VV)  /* 64,512,000 */

typedef float f32;

__device__ __forceinline__ f32 fast_tanh(f32 x){
    f32 e = __expf(2.0f*x);
    return 1.0f - 2.0f/(e+1.0f);   // exp=inf -> 1, exp=0 -> -1 : safe at extremes
}
__device__ __forceinline__ f32 fast_sig(f32 x){
    return 1.0f/(1.0f+__expf(-x));
}

// ---- init recurrent state: st = [h0_s0,h0_s1,c0_s0,c0_s1,h1_s0,h1_s1,c1_s0,c1_s1] x 32768
__global__ void k_init(const f32* __restrict__ h0in, const f32* __restrict__ c0in,
                       f32* __restrict__ st){
  int i = blockIdx.x*256 + threadIdx.x;
  if(i >= 2*BB*HIDD) return;
  int layer = i >> 15, r = i & 32767;
  st[(layer ? 4 : 0)*32768 + r] = h0in[i];
  st[(layer ? 6 : 2)*32768 + r] = c0in[i];
}

// ---- gather embeddings into lin_in[t][b][2048..2559]
__global__ void k_fill_emb(const f32* __restrict__ emb_table, const int* __restrict__ y,
                           f32* __restrict__ lin){
  int i = blockIdx.x*256 + threadIdx.x;
  if(i >= TT*BB*EMBD) return;
  int e = i & (EMBD-1);
  int tb = i >> 9; int b = tb & 31; int t = tb >> 5;
  int tok = y[b*64 + t];
  lin[(long)(t*BB+b)*LIND + 2048 + e] = emb_table[(long)tok*EMBD + e];
}

// ---- generic tiled fp32 GEMM: C = A(MxK) @ B, 64x64 tile, 4x4/thread.
// BT=false: B is (KxN); BT=true: B is (NxK) row-major (computes A @ B^T).
// EPI: 0 plain store, 1 tanh(x+bias), 2 x+bias scattered to logits layout.
template<int EPI, bool BT>
__global__ __launch_bounds__(256)
void k_gemm(const f32* __restrict__ A, const f32* __restrict__ Bm,
            const f32* __restrict__ bias, f32* __restrict__ C,
            int M, int N, int K, int lda, int ldb, int ldc){
  __shared__ f32 As[16][72];
  __shared__ f32 Bs[16][72];
  int tid = threadIdx.x;
  int row0 = blockIdx.x*64, col0 = blockIdx.y*64;
  int tx = tid & 15, ty = tid >> 4;
  f32 acc[4][4];
  #pragma unroll
  for(int i=0;i<4;i++)
    #pragma unroll
    for(int j=0;j<4;j++) acc[i][j]=0.f;
  int ra = tid>>2, ka = (tid&3)*4;   // A / BT loader: row ra, k-chunk ka
  int kb_ = tid>>4, nb = (tid&15)*4; // NN loader
  for(int k0=0;k0<K;k0+=16){
    {
      float4 a4 = make_float4(0.f,0.f,0.f,0.f);
      int gm = row0 + ra;
      if(gm < M) a4 = *(const float4*)(A + (long)gm*lda + k0 + ka);
      As[ka+0][ra]=a4.x; As[ka+1][ra]=a4.y; As[ka+2][ra]=a4.z; As[ka+3][ra]=a4.w;
    }
    if(BT){
      float4 b4 = make_float4(0.f,0.f,0.f,0.f);
      int gn = col0 + ra;
      if(gn < N) b4 = *(const float4*)(Bm + (long)gn*ldb + k0 + ka);
      Bs[ka+0][ra]=b4.x; Bs[ka+1][ra]=b4.y; Bs[ka+2][ra]=b4.z; Bs[ka+3][ra]=b4.w;
    } else {
      float4 b4 = *(const float4*)(Bm + (long)(k0+kb_)*ldb + col0 + nb);
      *(float4*)&Bs[kb_][nb] = b4;
    }
    __syncthreads();
    #pragma unroll
    for(int kk=0;kk<16;kk++){
      float4 av = *(const float4*)&As[kk][ty*4];
      float4 bv = *(const float4*)&Bs[kk][tx*4];
      const f32* af=(const f32*)&av; const f32* bf=(const f32*)&bv;
      #pragma unroll
      for(int i=0;i<4;i++)
        #pragma unroll
        for(int j=0;j<4;j++) acc[i][j] = __builtin_fmaf(af[i], bf[j], acc[i][j]);
    }
    __syncthreads();
  }
  #pragma unroll
  for(int i=0;i<4;i++){
    int gm = row0 + ty*4 + i;
    if(gm >= M) continue;
    #pragma unroll
    for(int j=0;j<4;j++){
      int gn = col0 + tx*4 + j;
      if(gn >= N) continue;
      f32 x = acc[i][j];
      if(EPI==0)      C[(long)gm*ldc + gn] = x;
      else if(EPI==1) C[(long)gm*ldc + gn] = fast_tanh(x + bias[gn]);
      else { int tt = gm>>5, b = gm&31; C[(long)b*TV + (long)tt*VV + gn] = x + bias[gn]; }
    }
  }
}

// ---- hWd[b][j] = sum_k h1[b][k] * Wd[k][j]   (128 blocks x 256)
__global__ void k_hWd(const f32* __restrict__ h1, const f32* __restrict__ Wd,
                      f32* __restrict__ hwd){
  int g = blockIdx.x*256 + threadIdx.x;   // b*1024 + j ; b uniform per block
  int b = g >> 10, j = g & 1023;
  const f32* h = h1 + b*HIDD;
  f32 a0=0.f,a1=0.f,a2=0.f,a3=0.f;
  for(int k=0;k<HIDD;k+=4){
    a0 = __builtin_fmaf(h[k+0], Wd[(k+0)*HIDD+j], a0);
    a1 = __builtin_fmaf(h[k+1], Wd[(k+1)*HIDD+j], a1);
    a2 = __builtin_fmaf(h[k+2], Wd[(k+2)*HIDD+j], a2);
    a3 = __builtin_fmaf(h[k+3], Wd[(k+3)*HIDD+j], a3);
  }
  hwd[g] = (a0+a1)+(a2+a3);
}

// ---- attention: score -> softmax -> ctx ; one block per batch row
__global__ void k_attn(const f32* __restrict__ enc_proj, const f32* __restrict__ enc_out,
                       const f32* __restrict__ hwd, const f32* __restrict__ vvec,
                       const int* __restrict__ mask, f32* __restrict__ lin,
                       f32* __restrict__ attw, int t){
  __shared__ f32 hw[HIDD];
  __shared__ f32 vv[HIDD];
  __shared__ f32 sc[SS];
  int b = blockIdx.x, tid = threadIdx.x;
  for(int i=tid;i<HIDD;i+=256){ hw[i]=hwd[b*HIDD+i]; vv[i]=vvec[i]; }
  __syncthreads();
  int wave = tid>>6, lane = tid&63;
  for(int s=wave; s<SS; s+=4){
    const f32* ep = enc_proj + (long)(b*SS+s)*HIDD;
    f32 p=0.f;
    for(int k=lane;k<HIDD;k+=64) p = __builtin_fmaf(vv[k], fast_tanh(ep[k]+hw[k]), p);
    for(int off=32;off;off>>=1) p += __shfl_down(p, off);
    if(lane==0) sc[s]=p;
  }
  __syncthreads();
  if(tid<64){
    int s=tid;
    f32 x = mask[b*SS+s] ? sc[s] : -1e9f;
    f32 m = x;
    for(int off=32;off;off>>=1) m = fmaxf(m, __shfl_xor(m, off));
    f32 e = __expf(x-m);
    f32 sum = e;
    for(int off=32;off;off>>=1) sum += __shfl_xor(sum, off);
    f32 w = e/sum;
    sc[s]=w;
    attw[(long)t*(BB*SS) + b*SS + s] = w;
  }
  __syncthreads();
  f32* ctx = lin + (long)(t*BB+b)*LIND + HIDD;
  for(int d=tid; d<ENCD; d+=256){
    f32 a=0.f;
    for(int s=0;s<SS;s++) a = __builtin_fmaf(sc[s], enc_out[(long)(b*SS+s)*ENCD + d], a);
    ctx[d]=a;
  }
}

// ---- LSTM0 gate partials: x=[emb(512),ctx(1024)] via W_ih0, h0 via W_hh0.
// grid (16 j-tiles, 16 k-chunks of 160). Each thread: one j, 32 batch accumulators.
__global__ void k_mm0(const f32* __restrict__ Wx, const f32* __restrict__ Wh,
                      const f32* __restrict__ bx, const f32* __restrict__ bh,
                      const f32* __restrict__ lin, const f32* __restrict__ h0c,
                      f32* __restrict__ part, int t){
  __shared__ f32 xs[BB][32];
  int j = blockIdx.x*256 + threadIdx.x;
  int c = blockIdx.y;
  int k0 = c*160;
  f32 acc[BB];
  #pragma unroll
  for(int b=0;b<BB;b++) acc[b]=0.f;
  for(int ks=0; ks<160; ks+=32){
    int kb = k0+ks;
    __syncthreads();
    for(int e=threadIdx.x; e<BB*32; e+=256){
      int b=e>>5, kk=e&31; int k=kb+kk;
      f32 xv;
      if(k<EMBD)      xv = lin[(long)(t*BB+b)*LIND + 2048 + k];
      else if(k<1536) xv = lin[(long)(t*BB+b)*LIND + 512 + k];
      else            xv = h0c[b*HIDD + (k-1536)];
      xs[b][kk]=xv;
    }
    __syncthreads();
    #pragma unroll
    for(int kk=0;kk<32;kk+=4){
      int k = kb+kk;
      float4 w4 = (k<1536) ? *(const float4*)(Wx + (long)j*1536 + k)
                           : *(const float4*)(Wh + (long)j*HIDD + (k-1536));
      const f32* wf = (const f32*)&w4;
      #pragma unroll
      for(int i=0;i<4;i++){
        f32 w = wf[i];
        #pragma unroll
        for(int b=0;b<BB;b++) acc[b] = __builtin_fmaf(xs[b][kk+i], w, acc[b]);
      }
    }
  }
  f32 bias = (c==0) ? (bx[j]+bh[j]) : 0.f;
  #pragma unroll
  for(int b=0;b<BB;b++) part[(long)(c*BB+b)*G4 + j] = acc[b] + bias;
}

// ---- LSTM1 gate partials: x=h0_new via W_ih1, h=h1_cur via W_hh1. chunks of 128.
__global__ void k_mm1(const f32* __restrict__ Wx, const f32* __restrict__ Wh,
                      const f32* __restrict__ bx, const f32* __restrict__ bh,
                      const f32* __restrict__ h0n, const f32* __restrict__ h1c,
                      f32* __restrict__ part){
  __shared__ f32 xs[BB][32];
  int j = blockIdx.x*256 + threadIdx.x;
  int c = blockIdx.y;
  int k0 = c*128;
  f32 acc[BB];
  #pragma unroll
  for(int b=0;b<BB;b++) acc[b]=0.f;
  for(int ks=0; ks<128; ks+=32){
    int kb = k0+ks;
    __syncthreads();
    for(int e=threadIdx.x; e<BB*32; e+=256){
      int b=e>>5, kk=e&31; int k=kb+kk;
      f32 xv = (k<HIDD) ? h0n[b*HIDD+k] : h1c[b*HIDD + (k-HIDD)];
      xs[b][kk]=xv;
    }
    __syncthreads();
    #pragma unroll
    for(int kk=0;kk<32;kk+=4){
      int k = kb+kk;
      float4 w4 = (k<HIDD) ? *(const float4*)(Wx + (long)j*HIDD + k)
                           : *(const float4*)(Wh + (long)j*HIDD + (k-HIDD));
      const f32* wf = (const f32*)&w4;
      #pragma unroll
      for(int i=0;i<4;i++){
        f32 w = wf[i];
        #pragma unroll
        for(int b=0;b<BB;b++) acc[b] = __builtin_fmaf(xs[b][kk+i], w, acc[b]);
      }
    }
  }
  f32 bias = (c==0) ? (bx[j]+bh[j]) : 0.f;
  #pragma unroll
  for(int b=0;b<BB;b++) part[(long)(c*BB+b)*G4 + j] = acc[b] + bias;
}

// ---- LSTM cell elementwise: sum 16 partials, apply gates. optionally write h into lin_in.
__global__ void k_cell(const f32* __restrict__ part, const f32* __restrict__ c_old,
                       f32* __restrict__ h_new, f32* __restrict__ c_new,
                       f32* __restrict__ lin_dst){
  int g = blockIdx.x*256 + threadIdx.x;  // 32768 = b*1024+j
  int b = g>>10, j = g&1023;
  f32 gi=0.f,gf=0.f,gg=0.f,go=0.f;
  #pragma unroll
  for(int c=0;c<16;c++){
    const f32* p = part + (long)(c*BB+b)*G4;
    gi += p[j]; gf += p[HIDD+j]; gg += p[2*HIDD+j]; go += p[3*HIDD+j];
  }
  f32 cc = fast_sig(gf)*c_old[g] + fast_sig(gi)*fast_tanh(gg);
  f32 hh = fast_sig(go)*fast_tanh(cc);
  c_new[g]=cc; h_new[g]=hh;
  if(lin_dst) lin_dst[(long)b*LIND + j] = hh;
}

extern "C" void kernel_launch(void* const* d_in, const int* in_sizes, int n_in,
                              void* d_out, int out_size, void* d_ws, size_t ws_size,
                              hipStream_t stream){
  (void)in_sizes; (void)n_in; (void)out_size; (void)ws_size;
  const f32* enc_output = (const f32*)d_in[0];
  const int* mask  = (const int*)d_in[1];
  const int* y     = (const int*)d_in[2];
  const f32* dec_h0= (const f32*)d_in[3];
  const f32* dec_c0= (const f32*)d_in[4];
  const f32* emb   = (const f32*)d_in[5];
  const f32* We    = (const f32*)d_in[6];
  const f32* Wd    = (const f32*)d_in[7];
  const f32* vvec  = (const f32*)d_in[8];
  const f32* W_ih0 = (const f32*)d_in[9];
  const f32* W_hh0 = (const f32*)d_in[10];
  const f32* b_ih0 = (const f32*)d_in[11];
  const f32* b_hh0 = (const f32*)d_in[12];
  const f32* W_ih1 = (const f32*)d_in[13];
  const f32* W_hh1 = (const f32*)d_in[14];
  const f32* b_ih1 = (const f32*)d_in[15];
  const f32* b_hh1 = (const f32*)d_in[16];
  const f32* out_W = (const f32*)d_in[17];
  const f32* out_b = (const f32*)d_in[18];
  const f32* sm_W  = (const f32*)d_in[19];
  const f32* sm_b  = (const f32*)d_in[20];
  f32* out = (f32*)d_out;
  f32* ws  = (f32*)d_ws;

  // ws layout (floats):
  f32* enc_proj = ws;              // 2,097,152  (B*S*HID)
  f32* lin      = ws + 2097152;    // 5,160,960  (T*B*2560: [h1|ctx|emb])
  f32* part     = ws + 7258112;    // 2,097,152  (16*B*4096) -- aliased with hidden
  f32* hidden   = ws + 7258112;    // 4,354,560  (2016*2160), phase-2 only
  f32* st       = ws + 11612672;   // 262,144    recurrent state ping-pong
  f32* hwd      = ws + 11874816;   // 32,768
  // total: 11,907,584 floats = 47.6 MB

  k_init<<<dim3(256), dim3(256), 0, stream>>>(dec_h0, dec_c0, st);
  k_fill_emb<<<dim3((TT*BB*EMBD+255)/256), dim3(256), 0, stream>>>(emb, y, lin);
  // enc_proj = enc_output @ We : (2048x1024)@(1024x1024) NN
  k_gemm<0,false><<<dim3(32,16), dim3(256), 0, stream>>>(
      enc_output, We, nullptr, enc_proj, BB*SS, HIDD, ENCD, ENCD, HIDD, HIDD);

  for(int t=0;t<TT;t++){
    int p = t&1, q = p^1;
    f32* h0c = st + (0+p)*32768; f32* h0n = st + (0+q)*32768;
    f32* c0c = st + (2+p)*32768; f32* c0n = st + (2+q)*32768;
    f32* h1c = st + (4+p)*32768; f32* h1n = st + (4+q)*32768;
    f32* c1c = st + (6+p)*32768; f32* c1n = st + (6+q)*32768;
    k_hWd<<<dim3(128), dim3(256), 0, stream>>>(h1c, Wd, hwd);
    k_attn<<<dim3(BB), dim3(256), 0, stream>>>(enc_proj, enc_output, hwd, vvec, mask,
                                               lin, out + OUT_ATT, t);
    k_mm0<<<dim3(16,16), dim3(256), 0, stream>>>(W_ih0, W_hh0, b_ih0, b_hh0, lin, h0c, part, t);
    k_cell<<<dim3(128), dim3(256), 0, stream>>>(part, c0c, h0n, c0n, (f32*)nullptr);
    k_mm1<<<dim3(16,16), dim3(256), 0, stream>>>(W_ih1, W_hh1, b_ih1, b_hh1, h0n, h1c, part);
    k_cell<<<dim3(128), dim3(256), 0, stream>>>(part, c1c, h1n, c1n, lin + (long)t*BB*LIND);
  }

  // hidden = tanh(lin @ out_W^T + out_b) : (2016x2560)@(2560x2160)
  k_gemm<1,true><<<dim3(32,34), dim3(256), 0, stream>>>(
      lin, out_W, out_b, hidden, TT*BB, INTERD, LIND, LIND, LIND, INTERD);
  // logits = hidden @ sm_W^T + sm_b -> scattered to (B,T,V)
  k_gemm<2,true><<<dim3(32,500), dim3(256), 0, stream>>>(
      hidden, sm_W, sm_b, out, TT*BB, VV, INTERD, INTERD, INTERD, 0);
}

// Round 2
// 23017.305 us; speedup vs baseline: 1.1801x; 1.1801x over previous
//
#include <hip/hip_runtime.h>
#include <hip/hip_bf16.h>

#define BB 32
#define SS 64
#define TT 63
#define EMBD 512
#define ENCD 1024
#define HIDD 1024
#define VV 32000
#define INTERD 2160
#define G4 4096
#define LIND 2560
#define TV (TT*VV)            /* 2,016,000 */
#define OUT_ATT ((long)BB*TT*VV)  /* 64,512,000 */

typedef float f32;
typedef __attribute__((ext_vector_type(8))) short bf16x8;
typedef __attribute__((ext_vector_type(4))) float f32x4;
typedef __attribute__((ext_vector_type(8))) unsigned short u16x8;

__device__ __forceinline__ f32 fast_tanh(f32 x){
    f32 e = __expf(2.0f*x);
    return 1.0f - 2.0f/(e+1.0f);
}
__device__ __forceinline__ f32 fast_sig(f32 x){
    return 1.0f/(1.0f+__expf(-x));
}
__device__ __forceinline__ unsigned short f2bf(f32 x){
    __hip_bfloat16 h = __float2bfloat16(x);  // RNE
    return *(unsigned short*)&h;
}
__device__ __forceinline__ void gl_lds16(const unsigned short* g, unsigned short* l){
  __builtin_amdgcn_global_load_lds((const __attribute__((address_space(1))) void*)g,
                                   (__attribute__((address_space(3))) void*)l, 16, 0, 0);
}

// ---- init recurrent state
__global__ void k_init(const f32* __restrict__ h0in, const f32* __restrict__ c0in,
                       f32* __restrict__ st){
  int i = blockIdx.x*256 + threadIdx.x;
  if(i >= 2*BB*HIDD) return;
  int layer = i >> 15, r = i & 32767;
  st[(layer ? 4 : 0)*32768 + r] = h0in[i];
  st[(layer ? 6 : 2)*32768 + r] = c0in[i];
}

// ---- gather embeddings into lin_in[t][b][2048..2559]
__global__ void k_fill_emb(const f32* __restrict__ emb_table, const int* __restrict__ y,
                           f32* __restrict__ lin){
  int i = blockIdx.x*256 + threadIdx.x;
  if(i >= TT*BB*EMBD) return;
  int e = i & (EMBD-1);
  int tb = i >> 9; int b = tb & 31; int t = tb >> 5;
  int tok = y[b*64 + t];
  lin[(long)(t*BB+b)*LIND + 2048 + e] = emb_table[(long)tok*EMBD + e];
}

// ---- fp32 tiled GEMM (only for enc_proj = enc_output @ We, NN)
__global__ __launch_bounds__(256)
void k_gemm_nn(const f32* __restrict__ A, const f32* __restrict__ Bm,
               f32* __restrict__ C, int M, int N, int K, int lda, int ldb, int ldc){
  __shared__ f32 As[16][72];
  __shared__ f32 Bs[16][72];
  int tid = threadIdx.x;
  int row0 = blockIdx.x*64, col0 = blockIdx.y*64;
  int tx = tid & 15, ty = tid >> 4;
  f32 acc[4][4];
  #pragma unroll
  for(int i=0;i<4;i++)
    #pragma unroll
    for(int j=0;j<4;j++) acc[i][j]=0.f;
  int ra = tid>>2, ka = (tid&3)*4;
  int kb_ = tid>>4, nb = (tid&15)*4;
  for(int k0=0;k0<K;k0+=16){
    {
      float4 a4 = make_float4(0.f,0.f,0.f,0.f);
      int gm = row0 + ra;
      if(gm < M) a4 = *(const float4*)(A + (long)gm*lda + k0 + ka);
      As[ka+0][ra]=a4.x; As[ka+1][ra]=a4.y; As[ka+2][ra]=a4.z; As[ka+3][ra]=a4.w;
    }
    {
      float4 b4 = *(const float4*)(Bm + (long)(k0+kb_)*ldb + col0 + nb);
      *(float4*)&Bs[kb_][nb] = b4;
    }
    __syncthreads();
    #pragma unroll
    for(int kk=0;kk<16;kk++){
      float4 av = *(const float4*)&As[kk][ty*4];
      float4 bv = *(const float4*)&Bs[kk][tx*4];
      const f32* af=(const f32*)&av; const f32* bf=(const f32*)&bv;
      #pragma unroll
      for(int i=0;i<4;i++)
        #pragma unroll
        for(int j=0;j<4;j++) acc[i][j] = __builtin_fmaf(af[i], bf[j], acc[i][j]);
    }
    __syncthreads();
  }
  #pragma unroll
  for(int i=0;i<4;i++){
    int gm = row0 + ty*4 + i;
    if(gm >= M) continue;
    #pragma unroll
    for(int j=0;j<4;j++){
      int gn = col0 + tx*4 + j;
      if(gn >= N) continue;
      C[(long)gm*ldc + gn] = acc[i][j];
    }
  }
}

// ---- fp32 row-major -> bf16 fragment-tiled layout.
// dst tile index = rsub*nkt + kt; within tile: lane*8 + j.
// element (r = rsub*16 + (lane&15), k = kt*32 + (lane>>4)*8 + j). OOB -> 0.
__global__ void k_conv(const f32* __restrict__ src, unsigned short* __restrict__ dst,
                       int ld, int rows, int kmax, int nkt, long ntiles){
  long g = (long)blockIdx.x*256 + threadIdx.x;
  long tile = g >> 6;
  if(tile >= ntiles) return;
  int lane = (int)(g & 63);
  int kt = (int)(tile % nkt);
  int rsub = (int)(tile / nkt);
  int r = rsub*16 + (lane&15);
  int k0 = kt*32 + ((lane>>4)<<3);
  u16x8 v;
  if(r < rows && (k0+8) <= kmax){
    float4 a = *(const float4*)(src + (long)r*ld + k0);
    float4 b = *(const float4*)(src + (long)r*ld + k0 + 4);
    v[0]=f2bf(a.x); v[1]=f2bf(a.y); v[2]=f2bf(a.z); v[3]=f2bf(a.w);
    v[4]=f2bf(b.x); v[5]=f2bf(b.y); v[6]=f2bf(b.z); v[7]=f2bf(b.w);
  } else {
    #pragma unroll
    for(int j=0;j<8;j++){
      int k = k0+j;
      f32 x = (r < rows && k < kmax) ? src[(long)r*ld + k] : 0.f;
      v[j] = f2bf(x);
    }
  }
  *(u16x8*)(dst + (tile<<9) + lane*8) = v;
}

// ---- bf16 MFMA GEMM: C(128x128 tile) = A_tiles @ B_tiles^T (both fragment-ordered).
// 4 waves (2x2), 64x64 per wave, BK=32, double-buffered LDS via global_load_lds w16.
// EPI==1: hidden = tanh(x + bias) -> bf16 A-fragment layout (nkt2=68), pad gn>=2160 -> 0
// EPI==2: logits: out[b*TV + t*VV + (n0+gn)] = x + bias[n0+gn], rows gm<2016 only
template<int NKT, int EPI>
__global__ __launch_bounds__(256)
void k_mfma(const unsigned short* __restrict__ At, const unsigned short* __restrict__ Bt,
            const f32* __restrict__ bias, void* __restrict__ Cout, int n0){
  __shared__ unsigned short smem[2][8192];   // [buf][ A 8*512 | B 8*512 ]
  const int tid = threadIdx.x;
  const int wid = tid >> 6, lane = tid & 63;
  const int wm = wid >> 1, wn = wid & 1;
  const int bm = blockIdx.x, bn = blockIdx.y;
  f32x4 acc[4][4] = {};

  // stage one K-step (BK=32): 16 subtiles of 1KB; wave w carries 4.
  auto stage = [&](int buf, int kt){
    #pragma unroll
    for(int i=0;i<4;i++){
      int idx = wid*4 + i;
      const unsigned short* g;
      int dst;
      if(idx < 8){ g = At + (((long)(bm*8 + idx)*NKT + kt) << 9) + lane*8;      dst = idx*512; }
      else       { g = Bt + (((long)(bn*8 + (idx-8))*NKT + kt) << 9) + lane*8;  dst = 4096 + (idx-8)*512; }
      gl_lds16(g, &smem[buf][dst]);
    }
  };

  stage(0, 0);
  for(int kt=0; kt<NKT; ++kt){
    const int cur = kt & 1;
    if(kt+1 < NKT){
      stage(cur^1, kt+1);
      asm volatile("s_waitcnt vmcnt(4)" ::: "memory");
    } else {
      asm volatile("s_waitcnt vmcnt(0)" ::: "memory");
    }
    __syncthreads();
    bf16x8 af[4], bfr[4];
    #pragma unroll
    for(int i=0;i<4;i++){
      af[i]  = *(const bf16x8*)&smem[cur][(wm*4 + i)*512 + lane*8];
      bfr[i] = *(const bf16x8*)&smem[cur][4096 + (wn*4 + i)*512 + lane*8];
    }
    #pragma unroll
    for(int mi=0;mi<4;mi++)
      #pragma unroll
      for(int ni=0;ni<4;ni++)
        acc[mi][ni] = __builtin_amdgcn_mfma_f32_16x16x32_bf16(af[mi], bfr[ni], acc[mi][ni], 0, 0, 0);
    __syncthreads();
  }

  // epilogue: C fragment mapping col = lane&15, row = (lane>>4)*4 + reg  [m89]
  #pragma unroll
  for(int mi=0;mi<4;mi++){
    #pragma unroll
    for(int ni=0;ni<4;ni++){
      #pragma unroll
      for(int r=0;r<4;r++){
        int gm = bm*128 + wm*64 + mi*16 + (lane>>4)*4 + r;
        int gn = bn*128 + wn*64 + ni*16 + (lane&15);
        f32 x = acc[mi][ni][r];
        if(EPI == 1){
          x = (gn < INTERD) ? fast_tanh(x + bias[gn]) : 0.f;
          unsigned short* hb = (unsigned short*)Cout;
          int msub = gm >> 4, ktile = gn >> 5;
          int lane_a = (gm & 15) + (((gn & 31) >> 3) << 4);
          int j = gn & 7;
          hb[(((long)(msub*68 + ktile)) << 9) + lane_a*8 + j] = f2bf(x);
        } else {
          if(gm < TT*BB){
            int gnn = n0 + gn;
            int t = gm >> 5, b = gm & 31;
            ((f32*)Cout)[(long)b*TV + (long)t*VV + gnn] = x + bias[gnn];
          }
        }
      }
    }
  }
}

// ---- hWd[b][j] = sum_k h1[b][k] * Wd[k][j]
__global__ void k_hWd(const f32* __restrict__ h1, const f32* __restrict__ Wd,
                      f32* __restrict__ hwd){
  int g = blockIdx.x*256 + threadIdx.x;
  int b = g >> 10, j = g & 1023;
  const f32* h = h1 + b*HIDD;
  f32 a0=0.f,a1=0.f,a2=0.f,a3=0.f;
  for(int k=0;k<HIDD;k+=4){
    a0 = __builtin_fmaf(h[k+0], Wd[(k+0)*HIDD+j], a0);
    a1 = __builtin_fmaf(h[k+1], Wd[(k+1)*HIDD+j], a1);
    a2 = __builtin_fmaf(h[k+2], Wd[(k+2)*HIDD+j], a2);
    a3 = __builtin_fmaf(h[k+3], Wd[(k+3)*HIDD+j], a3);
  }
  hwd[g] = (a0+a1)+(a2+a3);
}

// ---- attention
__global__ void k_attn(const f32* __restrict__ enc_proj, const f32* __restrict__ enc_out,
                       const f32* __restrict__ hwd, const f32* __restrict__ vvec,
                       const int* __restrict__ mask, f32* __restrict__ lin,
                       f32* __restrict__ attw, int t){
  __shared__ f32 hw[HIDD];
  __shared__ f32 vv[HIDD];
  __shared__ f32 sc[SS];
  int b = blockIdx.x, tid = threadIdx.x;
  for(int i=tid;i<HIDD;i+=256){ hw[i]=hwd[b*HIDD+i]; vv[i]=vvec[i]; }
  __syncthreads();
  int wave = tid>>6, lane = tid&63;
  for(int s=wave; s<SS; s+=4){
    const f32* ep = enc_proj + (long)(b*SS+s)*HIDD;
    f32 p=0.f;
    for(int k=lane;k<HIDD;k+=64) p = __builtin_fmaf(vv[k], fast_tanh(ep[k]+hw[k]), p);
    for(int off=32;off;off>>=1) p += __shfl_down(p, off);
    if(lane==0) sc[s]=p;
  }
  __syncthreads();
  if(tid<64){
    int s=tid;
    f32 x = mask[b*SS+s] ? sc[s] : -1e9f;
    f32 m = x;
    for(int off=32;off;off>>=1) m = fmaxf(m, __shfl_xor(m, off));
    f32 e = __expf(x-m);
    f32 sum = e;
    for(int off=32;off;off>>=1) sum += __shfl_xor(sum, off);
    f32 w = e/sum;
    sc[s]=w;
    attw[(long)t*(BB*SS) + b*SS + s] = w;
  }
  __syncthreads();
  f32* ctx = lin + (long)(t*BB+b)*LIND + HIDD;
  for(int d=tid; d<ENCD; d+=256){
    f32 a=0.f;
    for(int s=0;s<SS;s++) a = __builtin_fmaf(sc[s], enc_out[(long)(b*SS+s)*ENCD + d], a);
    ctx[d]=a;
  }
}

// ---- LSTM0 gate partials
__global__ void k_mm0(const f32* __restrict__ Wx, const f32* __restrict__ Wh,
                      const f32* __restrict__ bx, const f32* __restrict__ bh,
                      const f32* __restrict__ lin, const f32* __restrict__ h0c,
                      f32* __restrict__ part, int t){
  __shared__ f32 xs[BB][32];
  int j = blockIdx.x*256 + threadIdx.x;
  int c = blockIdx.y;
  int k0 = c*160;
  f32 acc[BB];
  #pragma unroll
  for(int b=0;b<BB;b++) acc[b]=0.f;
  for(int ks=0; ks<160; ks+=32){
    int kb = k0+ks;
    __syncthreads();
    for(int e=threadIdx.x; e<BB*32; e+=256){
      int b=e>>5, kk=e&31; int k=kb+kk;
      f32 xv;
      if(k<EMBD)      xv = lin[(long)(t*BB+b)*LIND + 2048 + k];
      else if(k<1536) xv = lin[(long)(t*BB+b)*LIND + 512 + k];
      else            xv = h0c[b*HIDD + (k-1536)];
      xs[b][kk]=xv;
    }
    __syncthreads();
    #pragma unroll
    for(int kk=0;kk<32;kk+=4){
      int k = kb+kk;
      float4 w4 = (k<1536) ? *(const float4*)(Wx + (long)j*1536 + k)
                           : *(const float4*)(Wh + (long)j*HIDD + (k-1536));
      const f32* wf = (const f32*)&w4;
      #pragma unroll
      for(int i=0;i<4;i++){
        f32 w = wf[i];
        #pragma unroll
        for(int b=0;b<BB;b++) acc[b] = __builtin_fmaf(xs[b][kk+i], w, acc[b]);
      }
    }
  }
  f32 bias = (c==0) ? (bx[j]+bh[j]) : 0.f;
  #pragma unroll
  for(int b=0;b<BB;b++) part[(long)(c*BB+b)*G4 + j] = acc[b] + bias;
}

// ---- LSTM1 gate partials
__global__ void k_mm1(const f32* __restrict__ Wx, const f32* __restrict__ Wh,
                      const f32* __restrict__ bx, const f32* __restrict__ bh,
                      const f32* __restrict__ h0n, const f32* __restrict__ h1c,
                      f32* __restrict__ part){
  __shared__ f32 xs[BB][32];
  int j = blockIdx.x*256 + threadIdx.x;
  int c = blockIdx.y;
  int k0 = c*128;
  f32 acc[BB];
  #pragma unroll
  for(int b=0;b<BB;b++) acc[b]=0.f;
  for(int ks=0; ks<128; ks+=32){
    int kb = k0+ks;
    __syncthreads();
    for(int e=threadIdx.x; e<BB*32; e+=256){
      int b=e>>5, kk=e&31; int k=kb+kk;
      f32 xv = (k<HIDD) ? h0n[b*HIDD+k] : h1c[b*HIDD + (k-HIDD)];
      xs[b][kk]=xv;
    }
    __syncthreads();
    #pragma unroll
    for(int kk=0;kk<32;kk+=4){
      int k = kb+kk;
      float4 w4 = (k<HIDD) ? *(const float4*)(Wx + (long)j*HIDD + k)
                           : *(const float4*)(Wh + (long)j*HIDD + (k-HIDD));
      const f32* wf = (const f32*)&w4;
      #pragma unroll
      for(int i=0;i<4;i++){
        f32 w = wf[i];
        #pragma unroll
        for(int b=0;b<BB;b++) acc[b] = __builtin_fmaf(xs[b][kk+i], w, acc[b]);
      }
    }
  }
  f32 bias = (c==0) ? (bx[j]+bh[j]) : 0.f;
  #pragma unroll
  for(int b=0;b<BB;b++) part[(long)(c*BB+b)*G4 + j] = acc[b] + bias;
}

// ---- LSTM cell elementwise
__global__ void k_cell(const f32* __restrict__ part, const f32* __restrict__ c_old,
                       f32* __restrict__ h_new, f32* __restrict__ c_new,
                       f32* __restrict__ lin_dst){
  int g = blockIdx.x*256 + threadIdx.x;
  int b = g>>10, j = g&1023;
  f32 gi=0.f,gf=0.f,gg=0.f,go=0.f;
  #pragma unroll
  for(int c=0;c<16;c++){
    const f32* p = part + (long)(c*BB+b)*G4;
    gi += p[j]; gf += p[HIDD+j]; gg += p[2*HIDD+j]; go += p[3*HIDD+j];
  }
  f32 cc = fast_sig(gf)*c_old[g] + fast_sig(gi)*fast_tanh(gg);
  f32 hh = fast_sig(go)*fast_tanh(cc);
  c_new[g]=cc; h_new[g]=hh;
  if(lin_dst) lin_dst[(long)b*LIND + j] = hh;
}

extern "C" void kernel_launch(void* const* d_in, const int* in_sizes, int n_in,
                              void* d_out, int out_size, void* d_ws, size_t ws_size,
                              hipStream_t stream){
  (void)in_sizes; (void)n_in; (void)out_size; (void)ws_size;
  const f32* enc_output = (const f32*)d_in[0];
  const int* mask  = (const int*)d_in[1];
  const int* y     = (const int*)d_in[2];
  const f32* dec_h0= (const f32*)d_in[3];
  const f32* dec_c0= (const f32*)d_in[4];
  const f32* emb   = (const f32*)d_in[5];
  const f32* We    = (const f32*)d_in[6];
  const f32* Wd    = (const f32*)d_in[7];
  const f32* vvec  = (const f32*)d_in[8];
  const f32* W_ih0 = (const f32*)d_in[9];
  const f32* W_hh0 = (const f32*)d_in[10];
  const f32* b_ih0 = (const f32*)d_in[11];
  const f32* b_hh0 = (const f32*)d_in[12];
  const f32* W_ih1 = (const f32*)d_in[13];
  const f32* W_hh1 = (const f32*)d_in[14];
  const f32* b_ih1 = (const f32*)d_in[15];
  const f32* b_hh1 = (const f32*)d_in[16];
  const f32* out_W = (const f32*)d_in[17];
  const f32* out_b = (const f32*)d_in[18];
  const f32* sm_W  = (const f32*)d_in[19];
  const f32* sm_b  = (const f32*)d_in[20];
  f32* out = (f32*)d_out;
  char* w8 = (char*)d_ws;

  // ws layout (bytes), total 95,879,168 (~91.4 MB):
  unsigned short* smW_bf  = (unsigned short*)(w8 + 0);          // 35,651,584 (chunk buf, 512 nsubs x 68 kt)
  unsigned short* outW_bf = (unsigned short*)(w8 + 35651584);   // 11,141,120 (136 x 80)
  f32*            lin     = (f32*)           (w8 + 46792704);   // 20,643,840 (2016 x 2560)
  unsigned short* lin_bf  = (unsigned short*)(w8 + 67436544);   // 10,485,760 (128 x 80)
  char*           loopr   =                   w8 + 77922304;    // 16,908,288 loop scratch / hid_bf alias
  f32* enc_proj = (f32*)loopr;                                  //  8,388,608
  f32* part     = (f32*)(loopr + 8388608);                      //  8,388,608
  f32* hwd      = (f32*)(loopr + 16777216);                     //    131,072
  unsigned short* hid_bf = (unsigned short*)loopr;              //  8,912,896 (post-loop, aliases enc_proj/part)
  f32* st       = (f32*)(w8 + 94830592);                        //  1,048,576

  k_init<<<dim3(256), dim3(256), 0, stream>>>(dec_h0, dec_c0, st);
  k_fill_emb<<<dim3((TT*BB*EMBD+255)/256), dim3(256), 0, stream>>>(emb, y, lin);
  k_gemm_nn<<<dim3(32,16), dim3(256), 0, stream>>>(
      enc_output, We, enc_proj, BB*SS, HIDD, ENCD, ENCD, HIDD, HIDD);
  // out_W (2160x2560) -> bf16 B-fragment tiles, n padded to 2176 (136 nsubs), nkt=80
  k_conv<<<dim3(2720), dim3(256), 0, stream>>>(out_W, outW_bf, LIND, INTERD, LIND, 80, 136L*80);

  for(int t=0;t<TT;t++){
    int p = t&1, q = p^1;
    f32* h0c = st + (0+p)*32768; f32* h0n = st + (0+q)*32768;
    f32* c0c = st + (2+p)*32768; f32* c0n = st + (2+q)*32768;
    f32* h1c = st + (4+p)*32768; f32* h1n = st + (4+q)*32768;
    f32* c1c = st + (6+p)*32768; f32* c1n = st + (6+q)*32768;
    k_hWd<<<dim3(128), dim3(256), 0, stream>>>(h1c, Wd, hwd);
    k_attn<<<dim3(BB), dim3(256), 0, stream>>>(enc_proj, enc_output, hwd, vvec, mask,
                                               lin, out + OUT_ATT, t);
    k_mm0<<<dim3(16,16), dim3(256), 0, stream>>>(W_ih0, W_hh0, b_ih0, b_hh0, lin, h0c, part, t);
    k_cell<<<dim3(128), dim3(256), 0, stream>>>(part, c0c, h0n, c0n, (f32*)nullptr);
    k_mm1<<<dim3(16,16), dim3(256), 0, stream>>>(W_ih1, W_hh1, b_ih1, b_hh1, h0n, h1c, part);
    k_cell<<<dim3(128), dim3(256), 0, stream>>>(part, c1c, h1n, c1n, lin + (long)t*BB*LIND);
  }

  // lin (2016x2560) -> bf16 A-fragment tiles (128 msubs x 80 kt), rows padded to 2048
  k_conv<<<dim3(2560), dim3(256), 0, stream>>>(lin, lin_bf, LIND, TT*BB, LIND, 80, 128L*80);
  // hidden = tanh(lin @ out_W^T + out_b) -> bf16 A-fragment tiles (128 x 68), K-pad 2160->2176
  k_mfma<80,1><<<dim3(16,17), dim3(256), 0, stream>>>(lin_bf, outW_bf, out_b, hid_bf, 0);

  // logits in 4 N-chunks: sm_W chunk -> bf16 B-fragment tiles, then MFMA GEMM
  for(int c=0;c<4;c++){
    int n0 = c*8192;
    int nsubs = (c<3) ? 512 : 464;          // 8192 / 7424 cols
    long ntiles = (long)nsubs*68;
    k_conv<<<dim3((unsigned)((ntiles*64+255)/256)), dim3(256), 0, stream>>>(
        sm_W + (long)n0*INTERD, smW_bf, INTERD, VV - n0, INTERD, 68, ntiles);
    k_mfma<68,2><<<dim3(16, nsubs/8), dim3(256), 0, stream>>>(
        hid_bf, smW_bf, sm_b, out, n0);
  }
}

// Round 3
// 19723.639 us; speedup vs baseline: 1.3771x; 1.1670x over previous
//
#include <hip/hip_runtime.h>
#include <hip/hip_bf16.h>

#define BB 32
#define SS 64
#define TT 63
#define EMBD 512
#define ENCD 1024
#define HIDD 1024
#define VV 32000
#define INTERD 2160
#define LIND 2560
#define TV (TT*VV)
#define OUT_ATT ((long)BB*TT*VV)

typedef float f32;
typedef unsigned short ushort_t;
typedef __attribute__((ext_vector_type(8))) short bf16x8;
typedef __attribute__((ext_vector_type(4))) float f32x4;
typedef __attribute__((ext_vector_type(8))) unsigned short u16x8;

// ---- ws layout (bytes) ----
#define OFF_LIN   0L
#define OFF_WD    20643840L
#define OFF_WHH0  (OFF_WD + 2097152L)
#define OFF_WIH0E (OFF_WHH0 + 8388608L)
#define OFF_WIH0C (OFF_WIH0E + 4194304L)
#define OFF_WIH1  (OFF_WIH0C + 8388608L)
#define OFF_WHH1  (OFF_WIH1 + 8388608L)
#define OFF_WEND  (OFF_WHH1 + 8388608L)      /* 60,489,728 */
#define OFF_LINBF OFF_WD                      /* post-loop alias over weights */
#define OFF_HIDBF (OFF_WD + 10485760L)
#define OFF_ENCP  OFF_WEND                    /* enc_proj f32, pre-loop only */
#define OFF_G0H   OFF_WEND                    /* loop partials alias enc_proj */
#define OFF_G1H   (OFF_G0H + 1048576L)
#define OFF_G0C   (OFF_G1H + 524288L)
#define OFF_G1X   (OFF_G0C + 2097152L)
#define OFF_HWD   (OFF_G1X + 2097152L)
#define OFF_EPB   (OFF_WEND + 8388608L)       /* enc_proj bf16 */
#define OFF_EOB   (OFF_EPB + 4194304L)        /* enc_out bf16 */
#define OFF_EMBF  (OFF_EOB + 4194304L)
#define OFF_C0    (OFF_EMBF + 2064384L)
#define OFF_C1    (OFF_C0 + 131072L)
#define OFF_H0F   (OFF_C1 + 131072L)
#define OFF_H1F   (OFF_H0F + 65536L)
#define OFF_CTXF  (OFF_H1F + 65536L)
#define OFF_CNT   (OFF_CTXF + 65536L)         /* 512B of counters */
/* total ~79.8 MB (< 91.4 MB known-safe from round 2) */

__device__ __forceinline__ f32 fast_tanh(f32 x){
    f32 e = __expf(2.0f*x);
    return 1.0f - 2.0f/(e+1.0f);
}
__device__ __forceinline__ f32 fast_sig(f32 x){
    return 1.0f/(1.0f+__expf(-x));
}
__device__ __forceinline__ ushort_t f2bf(f32 x){
    __hip_bfloat16 h = __float2bfloat16(x);
    return *(ushort_t*)&h;
}
__device__ __forceinline__ f32 bf2f(ushort_t u){
    unsigned v = ((unsigned)u) << 16;
    return __uint_as_float(v);
}

// ================= small setup kernels =================
__global__ void k_setup(const f32* __restrict__ c0in, f32* __restrict__ cst,
                        unsigned* __restrict__ cnt){
  int g = blockIdx.x*256 + threadIdx.x;
  if(g < 2*BB*HIDD) cst[g] = c0in[g];     // c0 then c1 contiguous
  if(g < 128) cnt[g] = 0;
}

__global__ void k_fill_emb(const f32* __restrict__ emb_table, const int* __restrict__ y,
                           f32* __restrict__ lin){
  int i = blockIdx.x*256 + threadIdx.x;
  if(i >= TT*BB*EMBD) return;
  int e = i & (EMBD-1);
  int tb = i >> 9; int b = tb & 31; int t = tb >> 5;
  int tok = y[b*64 + t];
  lin[(long)(t*BB+b)*LIND + 2048 + e] = emb_table[(long)tok*EMBD + e];
}

__global__ void k_cast(const f32* __restrict__ ep, const f32* __restrict__ eo,
                       ushort_t* __restrict__ epb, ushort_t* __restrict__ eob){
  int i = blockIdx.x*256 + threadIdx.x;
  if(i >= BB*SS*ENCD) return;
  epb[i] = f2bf(ep[i]);
  eob[i] = f2bf(eo[i]);
}

// ---- fp32 tiled GEMM (enc_proj = enc_output @ We, NN) -- validated round 1/2
__global__ __launch_bounds__(256)
void k_gemm_nn(const f32* __restrict__ A, const f32* __restrict__ Bm,
               f32* __restrict__ C, int M, int N, int K, int lda, int ldb, int ldc){
  __shared__ f32 As[16][72];
  __shared__ f32 Bs[16][72];
  int tid = threadIdx.x;
  int row0 = blockIdx.x*64, col0 = blockIdx.y*64;
  int tx = tid & 15, ty = tid >> 4;
  f32 acc[4][4];
  #pragma unroll
  for(int i=0;i<4;i++)
    #pragma unroll
    for(int j=0;j<4;j++) acc[i][j]=0.f;
  int ra = tid>>2, ka = (tid&3)*4;
  int kb_ = tid>>4, nb = (tid&15)*4;
  for(int k0=0;k0<K;k0+=16){
    {
      float4 a4 = make_float4(0.f,0.f,0.f,0.f);
      int gm = row0 + ra;
      if(gm < M) a4 = *(const float4*)(A + (long)gm*lda + k0 + ka);
      As[ka+0][ra]=a4.x; As[ka+1][ra]=a4.y; As[ka+2][ra]=a4.z; As[ka+3][ra]=a4.w;
    }
    {
      float4 b4 = *(const float4*)(Bm + (long)(k0+kb_)*ldb + col0 + nb);
      *(float4*)&Bs[kb_][nb] = b4;
    }
    __syncthreads();
    #pragma unroll
    for(int kk=0;kk<16;kk++){
      float4 av = *(const float4*)&As[kk][ty*4];
      float4 bv = *(const float4*)&Bs[kk][tx*4];
      const f32* af=(const f32*)&av; const f32* bf=(const f32*)&bv;
      #pragma unroll
      for(int i=0;i<4;i++)
        #pragma unroll
        for(int j=0;j<4;j++) acc[i][j] = __builtin_fmaf(af[i], bf[j], acc[i][j]);
    }
    __syncthreads();
  }
  #pragma unroll
  for(int i=0;i<4;i++){
    int gm = row0 + ty*4 + i;
    if(gm >= M) continue;
    #pragma unroll
    for(int j=0;j<4;j++){
      int gn = col0 + tx*4 + j;
      if(gn >= N) continue;
      C[(long)gm*ldc + gn] = acc[i][j];
    }
  }
}

// ---- fp32 -> bf16 fragment tiles. tile (rsub*nkt + kt): elem (r=rsub*16+(lane&15),
// k=kt*32+(lane>>4)*8+j). tr=false: src[r*ld+k]; tr=true: src[k*ld+r]. OOB->0.
__global__ void k_conv(const f32* __restrict__ src, ushort_t* __restrict__ dst,
                       int ld, int rows, int kmax, int nkt, long ntiles, int tr){
  long g = (long)blockIdx.x*256 + threadIdx.x;
  long tile = g >> 6;
  if(tile >= ntiles) return;
  int lane = (int)(g & 63);
  int kt = (int)(tile % nkt);
  int rsub = (int)(tile / nkt);
  int r = rsub*16 + (lane&15);
  int k0 = kt*32 + ((lane>>4)<<3);
  u16x8 v;
  if(!tr && r < rows && (k0+8) <= kmax){
    float4 a = *(const float4*)(src + (long)r*ld + k0);
    float4 b = *(const float4*)(src + (long)r*ld + k0 + 4);
    v[0]=f2bf(a.x); v[1]=f2bf(a.y); v[2]=f2bf(a.z); v[3]=f2bf(a.w);
    v[4]=f2bf(b.x); v[5]=f2bf(b.y); v[6]=f2bf(b.z); v[7]=f2bf(b.w);
  } else {
    #pragma unroll
    for(int j=0;j<8;j++){
      int k = k0+j;
      f32 x = 0.f;
      if(r < rows && k < kmax) x = tr ? src[(long)k*ld + r] : src[(long)r*ld + k];
      v[j] = f2bf(x);
    }
  }
  *(u16x8*)(dst + (tile<<9) + lane*8) = v;
}

// ================= persistent loop kernel =================
__device__ __forceinline__ void gemm_part(const ushort_t* __restrict__ Af, int ankt,
    const ushort_t* __restrict__ Bf, int bnkt, int ns, int kt0, int ktn,
    int lane, f32x4& acc0, f32x4& acc1){
  for(int kt=kt0; kt<kt0+ktn; ++kt){
    bf16x8 b  = *(const bf16x8*)(Bf + (((long)ns*bnkt + kt)<<9) + lane*8);
    bf16x8 a0 = *(const bf16x8*)(Af + (((long)kt)<<9) + lane*8);
    bf16x8 a1 = *(const bf16x8*)(Af + (((long)(ankt + kt))<<9) + lane*8);
    acc0 = __builtin_amdgcn_mfma_f32_16x16x32_bf16(a0, b, acc0, 0, 0, 0);
    acc1 = __builtin_amdgcn_mfma_f32_16x16x32_bf16(a1, b, acc1, 0, 0, 0);
  }
}
__device__ __forceinline__ void store_part(f32* __restrict__ dst, int ns, int lane,
                                           int nstride, const f32x4& acc0, const f32x4& acc1){
  int col = ns*16 + (lane&15);
  int r0 = (lane>>4)*4;
  #pragma unroll
  for(int r=0;r<4;r++){
    dst[(long)(r0+r)*nstride + col]    = acc0[r];
    dst[(long)(16+r0+r)*nstride + col] = acc1[r];
  }
}
// A-fragment address for element (row b<32, k): byte-free element index
__device__ __forceinline__ long frag_idx(int b, int k, int nkt){
  return (((long)((b>>4)*nkt + (k>>5)))<<9) + ((b&15) + (((k&31)>>3)<<4))*8 + (k&7);
}

__device__ __forceinline__ void gbar(unsigned* __restrict__ cnt, unsigned target){
  __syncthreads();
  if(threadIdx.x == 0){
    __threadfence();
    __hip_atomic_fetch_add(&cnt[(blockIdx.x & 7)*16], 1u,
                           __ATOMIC_RELEASE, __HIP_MEMORY_SCOPE_AGENT);
    for(;;){
      unsigned sum = 0;
      #pragma unroll
      for(int i=0;i<8;i++)
        sum += __hip_atomic_load(&cnt[i*16], __ATOMIC_RELAXED, __HIP_MEMORY_SCOPE_AGENT);
      if(sum >= target) break;
      __builtin_amdgcn_s_sleep(4);
    }
    __threadfence();
  }
  __syncthreads();
}

__global__ __launch_bounds__(256, 2)
void k_loop(char* __restrict__ ws, const f32* __restrict__ vvec,
            const int* __restrict__ maskp,
            const f32* __restrict__ b_ih0, const f32* __restrict__ b_hh0,
            const f32* __restrict__ b_ih1, const f32* __restrict__ b_hh1,
            f32* __restrict__ out){
  f32* lin = (f32*)(ws + OFF_LIN);
  const ushort_t* Wdt   = (const ushort_t*)(ws + OFF_WD);
  const ushort_t* Whh0  = (const ushort_t*)(ws + OFF_WHH0);
  const ushort_t* Wih0e = (const ushort_t*)(ws + OFF_WIH0E);
  const ushort_t* Wih0c = (const ushort_t*)(ws + OFF_WIH0C);
  const ushort_t* Wih1  = (const ushort_t*)(ws + OFF_WIH1);
  const ushort_t* Whh1  = (const ushort_t*)(ws + OFF_WHH1);
  f32* g0h = (f32*)(ws + OFF_G0H);      // [2][32][4096]
  f32* g1h = (f32*)(ws + OFF_G1H);      // [32][4096]
  f32* g0c = (f32*)(ws + OFF_G0C);      // [4][32][4096]
  f32* g1x = (f32*)(ws + OFF_G1X);      // [4][32][4096]
  f32* hwd = (f32*)(ws + OFF_HWD);      // [4][32][1024]
  const ushort_t* epb  = (const ushort_t*)(ws + OFF_EPB);
  const ushort_t* eob  = (const ushort_t*)(ws + OFF_EOB);
  const ushort_t* embf = (const ushort_t*)(ws + OFF_EMBF);
  f32* c0 = (f32*)(ws + OFF_C0);
  f32* c1 = (f32*)(ws + OFF_C1);
  ushort_t* h0f  = (ushort_t*)(ws + OFF_H0F);
  ushort_t* h1f  = (ushort_t*)(ws + OFF_H1F);
  ushort_t* ctxf = (ushort_t*)(ws + OFF_CTXF);
  unsigned* cnt  = (unsigned*)(ws + OFF_CNT);
  f32* attw = out + OUT_ATT;

  const int tid = threadIdx.x, wid = tid >> 6, lane = tid & 63;
  const int blk = blockIdx.x;
  const int gw = blk*4 + wid;           // 0..1023
  __shared__ f32 hw[HIDD];
  __shared__ f32 sc[SS];
  __shared__ f32 wsm[SS];

  f32 vvr[16];
  #pragma unroll
  for(int i=0;i<16;i++) vvr[i] = vvec[lane + 64*i];

  unsigned bar = 0;
  for(int t=0; t<TT; ++t){
    // ---------- Phase A: g0h (+emb part), g1h, hWd ----------
    {
      f32x4 a0 = {0.f,0.f,0.f,0.f}, a1 = {0.f,0.f,0.f,0.f};
      if(gw < 512){
        int ns = gw & 255, kp = gw >> 8;
        gemm_part(h0f, 32, Whh0, 32, ns, kp*16, 16, lane, a0, a1);
        if(kp == 0)
          gemm_part(embf + (long)t*16384, 16, Wih0e, 16, ns, 0, 16, lane, a0, a1);
        store_part(g0h + (long)kp*131072, ns, lane, 4096, a0, a1);
      } else if(gw < 768){
        int ns = gw - 512;
        gemm_part(h1f, 32, Whh1, 32, ns, 0, 32, lane, a0, a1);
        store_part(g1h, ns, lane, 4096, a0, a1);
      } else {
        int l = gw - 768, ns = l & 63, kp = l >> 6;
        gemm_part(h1f, 32, Wdt, 32, ns, kp*8, 8, lane, a0, a1);
        store_part(hwd + (long)kp*32768, ns, lane, 1024, a0, a1);
      }
    }
    bar += 256; gbar(cnt, bar);
    // ---------- Phase B: attention (blocks 0..127: b=blk>>2, dc=blk&3) ----------
    if(blk < 128){
      int b = blk >> 2, dc = blk & 3;
      for(int j=tid; j<HIDD; j+=256)
        hw[j] = hwd[b*1024+j] + hwd[32768 + b*1024+j]
              + hwd[65536 + b*1024+j] + hwd[98304 + b*1024+j];
      __syncthreads();
      #pragma unroll 1
      for(int si=0; si<16; ++si){
        int s = wid*16 + si;
        const ushort_t* ep = epb + ((long)(b*64+s)<<10);
        f32 p = 0.f;
        #pragma unroll
        for(int i=0;i<16;i++){
          f32 e = bf2f(ep[lane + 64*i]);
          p = __builtin_fmaf(vvr[i], fast_tanh(e + hw[lane + 64*i]), p);
        }
        #pragma unroll
        for(int off=32; off; off>>=1) p += __shfl_down(p, off);
        if(lane == 0) sc[s] = p;
      }
      __syncthreads();
      if(tid < 64){
        int s = tid;
        f32 x = maskp[b*64+s] ? sc[s] : -1e9f;
        f32 m = x;
        #pragma unroll
        for(int off=32; off; off>>=1) m = fmaxf(m, __shfl_xor(m, off));
        f32 e = __expf(x - m);
        f32 sum = e;
        #pragma unroll
        for(int off=32; off; off>>=1) sum += __shfl_xor(sum, off);
        f32 w = e/sum;
        wsm[s] = w;
        if(dc == 0) attw[(long)t*(BB*SS) + b*64 + s] = w;
      }
      __syncthreads();
      {
        int d = dc*256 + tid;
        const ushort_t* eo = eob + ((long)b<<16) + d;
        f32 a = 0.f;
        #pragma unroll 8
        for(int s=0;s<64;s++) a = __builtin_fmaf(wsm[s], bf2f(eo[(long)s<<10]), a);
        lin[(long)(t*BB+b)*LIND + HIDD + d] = a;
        ctxf[frag_idx(b, d, 32)] = f2bf(a);
      }
    }
    bar += 256; gbar(cnt, bar);
    // ---------- Phase C: g0c = ctx @ Wih0c^T (ksplit 4) ----------
    {
      f32x4 a0 = {0.f,0.f,0.f,0.f}, a1 = {0.f,0.f,0.f,0.f};
      int ns = gw & 255, kp = gw >> 8;
      gemm_part(ctxf, 32, Wih0c, 32, ns, kp*8, 8, lane, a0, a1);
      store_part(g0c + (long)kp*131072, ns, lane, 4096, a0, a1);
    }
    bar += 256; gbar(cnt, bar);
    // ---------- Phase D: cell0 ----------
    {
      int g = blk*256 + tid;
      if(g < BB*HIDD){
        int b = g >> 10, j = g & 1023;
        long base = (long)b*4096;
        f32 gv[4];
        #pragma unroll
        for(int q=0;q<4;q++){
          int idx = q*1024 + j;
          f32 s = g0h[base+idx] + g0h[131072+base+idx]
                + g0c[base+idx] + g0c[131072+base+idx]
                + g0c[262144+base+idx] + g0c[393216+base+idx]
                + b_ih0[idx] + b_hh0[idx];
          gv[q] = s;
        }
        f32 cc = fast_sig(gv[1])*c0[g] + fast_sig(gv[0])*fast_tanh(gv[2]);
        f32 hh = fast_sig(gv[3])*fast_tanh(cc);
        c0[g] = cc;
        h0f[frag_idx(b, j, 32)] = f2bf(hh);
      }
    }
    bar += 256; gbar(cnt, bar);
    // ---------- Phase E: g1x = h0_new @ Wih1^T (ksplit 4) ----------
    {
      f32x4 a0 = {0.f,0.f,0.f,0.f}, a1 = {0.f,0.f,0.f,0.f};
      int ns = gw & 255, kp = gw >> 8;
      gemm_part(h0f, 32, Wih1, 32, ns, kp*8, 8, lane, a0, a1);
      store_part(g1x + (long)kp*131072, ns, lane, 4096, a0, a1);
    }
    bar += 256; gbar(cnt, bar);
    // ---------- Phase F: cell1 ----------
    {
      int g = blk*256 + tid;
      if(g < BB*HIDD){
        int b = g >> 10, j = g & 1023;
        long base = (long)b*4096;
        f32 gv[4];
        #pragma unroll
        for(int q=0;q<4;q++){
          int idx = q*1024 + j;
          f32 s = g1h[base+idx]
                + g1x[base+idx] + g1x[131072+base+idx]
                + g1x[262144+base+idx] + g1x[393216+base+idx]
                + b_ih1[idx] + b_hh1[idx];
          gv[q] = s;
        }
        f32 cc = fast_sig(gv[1])*c1[g] + fast_sig(gv[0])*fast_tanh(gv[2]);
        f32 hh = fast_sig(gv[3])*fast_tanh(cc);
        c1[g] = cc;
        lin[(long)(t*BB+b)*LIND + j] = hh;
        h1f[frag_idx(b, j, 32)] = f2bf(hh);
      }
    }
    bar += 256; gbar(cnt, bar);
  }
}

// ================= phase-2 MFMA GEMM, B converted inline from f32 =================
// C(128x128) = A_frags @ B^T. A from frag tiles; B f32 row-major (nrowsB x ldb),
// guarded by nrowsB/kmaxB. EPI1: tanh(x+bias)->hid_bf frags (nkt 68). EPI2: logits.
template<int NKT, int EPI>
__global__ __launch_bounds__(256)
void k_mfma2(const ushort_t* __restrict__ At, const f32* __restrict__ B,
             int ldb, int nrowsB, int kmaxB,
             const f32* __restrict__ bias, void* __restrict__ Cout){
  const int tid = threadIdx.x, wid = tid >> 6, lane = tid & 63;
  const int wm = wid >> 1, wn = wid & 1;
  const int bm = blockIdx.x, bn = blockIdx.y;
  f32x4 acc[4][4] = {};
  const int rbase = bn*128 + wn*64 + (lane&15);
  const int kb = (lane>>4)*8;
  for(int kt=0; kt<NKT; ++kt){
    bf16x8 af[4], bfr[4];
    #pragma unroll
    for(int i=0;i<4;i++)
      af[i] = *(const bf16x8*)(At + (((long)(bm*8 + wm*4 + i)*NKT + kt)<<9) + lane*8);
    int k0 = kt*32 + kb;
    #pragma unroll
    for(int i=0;i<4;i++){
      int r = rbase + i*16;
      u16x8 v;
      if(r < nrowsB && (k0+8) <= kmaxB){
        float4 x = *(const float4*)(B + (long)r*ldb + k0);
        float4 y = *(const float4*)(B + (long)r*ldb + k0 + 4);
        v[0]=f2bf(x.x); v[1]=f2bf(x.y); v[2]=f2bf(x.z); v[3]=f2bf(x.w);
        v[4]=f2bf(y.x); v[5]=f2bf(y.y); v[6]=f2bf(y.z); v[7]=f2bf(y.w);
      } else {
        #pragma unroll
        for(int j=0;j<8;j++){
          int k = k0+j;
          f32 xx = (r < nrowsB && k < kmaxB) ? B[(long)r*ldb + k] : 0.f;
          v[j] = f2bf(xx);
        }
      }
      bfr[i] = *(bf16x8*)&v;
    }
    #pragma unroll
    for(int mi=0;mi<4;mi++)
      #pragma unroll
      for(int ni=0;ni<4;ni++)
        acc[mi][ni] = __builtin_amdgcn_mfma_f32_16x16x32_bf16(af[mi], bfr[ni], acc[mi][ni], 0, 0, 0);
  }
  #pragma unroll
  for(int mi=0;mi<4;mi++){
    #pragma unroll
    for(int ni=0;ni<4;ni++){
      #pragma unroll
      for(int r=0;r<4;r++){
        int gm = bm*128 + wm*64 + mi*16 + (lane>>4)*4 + r;
        int gn = bn*128 + wn*64 + ni*16 + (lane&15);
        f32 x = acc[mi][ni][r];
        if(EPI == 1){
          x = (gn < INTERD) ? fast_tanh(x + bias[gn]) : 0.f;
          ushort_t* hb = (ushort_t*)Cout;
          int msub = gm >> 4, ktile = gn >> 5;
          int lane_a = (gm & 15) + (((gn & 31) >> 3) << 4);
          hb[(((long)(msub*68 + ktile)) << 9) + lane_a*8 + (gn & 7)] = f2bf(x);
        } else {
          if(gm < TT*BB){
            int tt = gm >> 5, b = gm & 31;
            ((f32*)Cout)[(long)b*TV + (long)tt*VV + gn] = x + bias[gn];
          }
        }
      }
    }
  }
}

extern "C" void kernel_launch(void* const* d_in, const int* in_sizes, int n_in,
                              void* d_out, int out_size, void* d_ws, size_t ws_size,
                              hipStream_t stream){
  (void)in_sizes; (void)n_in; (void)out_size; (void)ws_size;
  const f32* enc_output = (const f32*)d_in[0];
  const int* mask  = (const int*)d_in[1];
  const int* y     = (const int*)d_in[2];
  const f32* dec_h0= (const f32*)d_in[3];
  const f32* dec_c0= (const f32*)d_in[4];
  const f32* emb   = (const f32*)d_in[5];
  const f32* We    = (const f32*)d_in[6];
  const f32* Wd    = (const f32*)d_in[7];
  const f32* vvec  = (const f32*)d_in[8];
  const f32* W_ih0 = (const f32*)d_in[9];
  const f32* W_hh0 = (const f32*)d_in[10];
  const f32* b_ih0 = (const f32*)d_in[11];
  const f32* b_hh0 = (const f32*)d_in[12];
  const f32* W_ih1 = (const f32*)d_in[13];
  const f32* W_hh1 = (const f32*)d_in[14];
  const f32* b_ih1 = (const f32*)d_in[15];
  const f32* b_hh1 = (const f32*)d_in[16];
  const f32* out_W = (const f32*)d_in[17];
  const f32* out_b = (const f32*)d_in[18];
  const f32* sm_W  = (const f32*)d_in[19];
  const f32* sm_b  = (const f32*)d_in[20];
  f32* out = (f32*)d_out;
  char* ws = (char*)d_ws;

  f32* lin       = (f32*)(ws + OFF_LIN);
  f32* enc_proj  = (f32*)(ws + OFF_ENCP);
  ushort_t* epb  = (ushort_t*)(ws + OFF_EPB);
  ushort_t* eob  = (ushort_t*)(ws + OFF_EOB);
  ushort_t* lin_bf = (ushort_t*)(ws + OFF_LINBF);
  ushort_t* hid_bf = (ushort_t*)(ws + OFF_HIDBF);

  // ---- setup ----
  k_setup<<<dim3(256), dim3(256), 0, stream>>>(dec_c0, (f32*)(ws + OFF_C0),
                                               (unsigned*)(ws + OFF_CNT));
  k_fill_emb<<<dim3(4032), dim3(256), 0, stream>>>(emb, y, lin);
  k_gemm_nn<<<dim3(32,16), dim3(256), 0, stream>>>(
      enc_output, We, enc_proj, BB*SS, HIDD, ENCD, ENCD, HIDD, HIDD);
  k_cast<<<dim3(8192), dim3(256), 0, stream>>>(enc_proj, enc_output, epb, eob);

  // ---- weight / state conversions to bf16 fragment tiles ----
  // Wd TRANSPOSED (need Wd[k][j] as B[n=j][k])
  k_conv<<<dim3(512),  dim3(256), 0, stream>>>(Wd,        (ushort_t*)(ws+OFF_WD),   HIDD, HIDD, HIDD, 32, 64L*32, 1);
  k_conv<<<dim3(2048), dim3(256), 0, stream>>>(W_hh0,     (ushort_t*)(ws+OFF_WHH0), HIDD, 4096, HIDD, 32, 256L*32, 0);
  k_conv<<<dim3(1024), dim3(256), 0, stream>>>(W_ih0,     (ushort_t*)(ws+OFF_WIH0E),1536, 4096, 512,  16, 256L*16, 0);
  k_conv<<<dim3(2048), dim3(256), 0, stream>>>(W_ih0+512, (ushort_t*)(ws+OFF_WIH0C),1536, 4096, HIDD, 32, 256L*32, 0);
  k_conv<<<dim3(2048), dim3(256), 0, stream>>>(W_ih1,     (ushort_t*)(ws+OFF_WIH1), HIDD, 4096, HIDD, 32, 256L*32, 0);
  k_conv<<<dim3(2048), dim3(256), 0, stream>>>(W_hh1,     (ushort_t*)(ws+OFF_WHH1), HIDD, 4096, HIDD, 32, 256L*32, 0);
  // emb frags for all t: rows 2016, K 512 -> per-t 32 contiguous tiles
  k_conv<<<dim3(504),  dim3(256), 0, stream>>>(lin+2048,  (ushort_t*)(ws+OFF_EMBF), LIND, TT*BB, 512, 16, 126L*16, 0);
  // h0f / h1f initial state
  k_conv<<<dim3(16),   dim3(256), 0, stream>>>(dec_h0,        (ushort_t*)(ws+OFF_H0F), HIDD, BB, HIDD, 32, 64, 0);
  k_conv<<<dim3(16),   dim3(256), 0, stream>>>(dec_h0+32768,  (ushort_t*)(ws+OFF_H1F), HIDD, BB, HIDD, 32, 64, 0);

  // ---- the 63-step recurrence: ONE persistent kernel ----
  k_loop<<<dim3(256), dim3(256), 0, stream>>>(ws, vvec, mask,
      b_ih0, b_hh0, b_ih1, b_hh1, out);

  // ---- phase 2 ----
  k_conv<<<dim3(2560), dim3(256), 0, stream>>>(lin, lin_bf, LIND, TT*BB, LIND, 80, 128L*80, 0);
  // hidden = tanh(lin @ out_W^T + out_b) -> bf16 A-frags (nkt 68)
  k_mfma2<80,1><<<dim3(16,17), dim3(256), 0, stream>>>(
      lin_bf, out_W, LIND, INTERD, LIND, out_b, hid_bf);
  // logits = hidden @ sm_W^T + sm_b  (N = 32000 = 250 x 128)
  k_mfma2<68,2><<<dim3(16,250), dim3(256), 0, stream>>>(
      hid_bf, sm_W, INTERD, VV, INTERD, sm_b, out);
}